// Round 11
// baseline (355.832 us; speedup 1.0000x reference)
//
#include <hip/hip_runtime.h>

#define N_NODES 50000
#define N_EDGES 1600000
#define DIM_IN  512
#define DIM_HID 64
#define DIM_OUT 7
#define NBUCK   196          // ceil(N_NODES/256) dst buckets
#define PART_BLOCKS 256

using u16 = unsigned short;
using bf16x8 = __attribute__((ext_vector_type(8))) __bf16;
using f32x4  = __attribute__((ext_vector_type(4))) float;

__device__ __forceinline__ float bf2f(u16 u) {
    union { float f; unsigned int i; } v;
    v.i = ((unsigned int)u) << 16;
    return v.f;
}

__device__ __forceinline__ u16 f2bf(float f) {
    union { float f; unsigned int i; } v;
    v.f = f;
    unsigned int r = 0x7FFFu + ((v.i >> 16) & 1u);
    return (u16)((v.i + r) >> 16);
}

// ---- on-device input-encoding detection (proven rounds 2-10) ----
__global__ void k_detect(const u16* __restrict__ xw, const int* __restrict__ ei32,
                         int* __restrict__ flags) {
    if (threadIdx.x == 0 && blockIdx.x == 0) {
        int sane = 0;
        for (int i = 0; i < 256; ++i) {
            u16 w = xw[2 * i];
            int e = (w >> 7) & 0xFF;
            if (e >= 100 && e <= 140) sane++;
        }
        flags[0] = (sane >= 200) ? 0 : 1;
        int nz = 0;
        for (int i = 0; i < 256; ++i)
            if (ei32[2 * i + 1] != 0) nz++;
        flags[1] = (nz == 0) ? 1 : 0;
    }
}

__device__ __forceinline__ int ld_edge(const int* ei, int i64f, size_t idx) {
    if (i64f) return (int)((const long long*)ei)[idx];
    return ei[idx];
}

// ---- pass 1: per-block bin counts -> cnt[bin][block] + global bin sums ----
__global__ void k_count(const int* __restrict__ ei, const int* __restrict__ flags,
                        int* __restrict__ gbsum, int* __restrict__ cnt) {
    __shared__ int hist[NBUCK];
    int t = threadIdx.x;
    int i64f = flags[1];
    const int CH = (N_EDGES + PART_BLOCKS - 1) / PART_BLOCKS;  // 6250
    int lo = blockIdx.x * CH;
    int hi = lo + CH; if (hi > N_EDGES) hi = N_EDGES;
    if (t < NBUCK) hist[t] = 0;
    __syncthreads();
    for (int i = lo + t; i < hi; i += 256) {
        int s = ld_edge(ei, i64f, (size_t)i);
        int d = ld_edge(ei, i64f, (size_t)N_EDGES + i);
        if ((unsigned)d < (unsigned)N_NODES && (unsigned)s < (unsigned)N_NODES)
            atomicAdd(&hist[d >> 8], 1);
    }
    __syncthreads();
    if (t < NBUCK) {
        int h = hist[t];
        cnt[t * PART_BLOCKS + blockIdx.x] = h;
        if (h > 0) atomicAdd(&gbsum[t], h);
    }
}

// ---- exclusive scan of bucket sums -> bbase; total -> rowptr[N] ----
__global__ void k_s2(const int* __restrict__ gbsum, int* __restrict__ bbase,
                     int* __restrict__ rowptr) {
    __shared__ int sc[256];
    int t = threadIdx.x;
    int v = (t < NBUCK) ? gbsum[t] : 0;
    sc[t] = v;
    __syncthreads();
    for (int off = 1; off < 256; off <<= 1) {
        int u = (t >= off) ? sc[t - off] : 0;
        __syncthreads();
        sc[t] += u;
        __syncthreads();
    }
    if (t < NBUCK) bbase[t] = sc[t] - v;
    if (t == 255) rowptr[N_NODES] = sc[255];
}

// ---- per-bin scan over blocks: cnt[bin][blk] -> absolute write base ----
__global__ void k_pb(const int* __restrict__ bbase, int* __restrict__ cnt) {
    __shared__ int sc[256];
    int b = blockIdx.x, t = threadIdx.x;
    int v = cnt[b * PART_BLOCKS + t];
    sc[t] = v;
    __syncthreads();
    for (int off = 1; off < 256; off <<= 1) {
        int u = (t >= off) ? sc[t - off] : 0;
        __syncthreads();
        sc[t] += u;
        __syncthreads();
    }
    cnt[b * PART_BLOCKS + t] = bbase[b] + sc[t] - v;
}

// ---- pass 2: single-pass scatter into bucket-sorted ebuf, packed (src<<8|d&255) ----
__global__ void k_part(const int* __restrict__ ei, const int* __restrict__ flags,
                       const int* __restrict__ cnt, unsigned int* __restrict__ ebuf) {
    __shared__ int cur[NBUCK];
    int t = threadIdx.x, blk = blockIdx.x;
    int i64f = flags[1];
    const int CH = (N_EDGES + PART_BLOCKS - 1) / PART_BLOCKS;
    int lo = blk * CH;
    int hi = lo + CH; if (hi > N_EDGES) hi = N_EDGES;
    if (t < NBUCK) cur[t] = cnt[t * PART_BLOCKS + blk];
    __syncthreads();
    for (int i = lo + t; i < hi; i += 256) {
        int s = ld_edge(ei, i64f, (size_t)i);
        int d = ld_edge(ei, i64f, (size_t)N_EDGES + i);
        if ((unsigned)d < (unsigned)N_NODES && (unsigned)s < (unsigned)N_NODES) {
            int pos = atomicAdd(&cur[d >> 8], 1);
            if ((unsigned)pos < (unsigned)N_EDGES)
                ebuf[pos] = ((unsigned)s << 8) | (unsigned)(d & 255);
        }
    }
}

// ---- per-bucket: LDS degree histogram -> rowptr + dinv + CSR fill ----
__global__ void k_cfill(const unsigned int* __restrict__ ebuf,
                        const int* __restrict__ bbase, const int* __restrict__ gbsum,
                        int* __restrict__ rowptr, float* __restrict__ dinv,
                        int* __restrict__ col) {
    __shared__ int dcnt[256];
    __shared__ int sc[256];
    __shared__ int cur[256];
    int b = blockIdx.x, t = threadIdx.x;
    int e0 = bbase[b];
    int e1 = e0 + gbsum[b];
    dcnt[t] = 0;
    __syncthreads();
    for (int e = e0 + t; e < e1; e += 256)
        atomicAdd(&dcnt[ebuf[e] & 255u], 1);
    __syncthreads();
    int v = dcnt[t];
    sc[t] = v;
    __syncthreads();
    for (int off = 1; off < 256; off <<= 1) {
        int u = (t >= off) ? sc[t - off] : 0;
        __syncthreads();
        sc[t] += u;
        __syncthreads();
    }
    int row0 = e0 + sc[t] - v;
    cur[t] = row0;
    int idx = b * 256 + t;
    if (idx < N_NODES) {
        rowptr[idx] = row0;
        dinv[idx] = rsqrtf((float)(v + 1));  // +1 self-loop
    }
    __syncthreads();
    for (int e = e0 + t; e < e1; e += 256) {
        unsigned int x = ebuf[e];
        int p = atomicAdd(&cur[x & 255u], 1);
        if ((unsigned)p < (unsigned)N_EDGES) col[p] = (int)(x >> 8);
    }
}

// ---- W1T[n][k] = bf16(W1[k][n]) ----
__global__ void k_tw1(const void* __restrict__ W1, const int* __restrict__ flags,
                      u16* __restrict__ W1T) {
    int i = blockIdx.x * blockDim.x + threadIdx.x;
    if (i < DIM_IN * DIM_HID) {
        int n = i >> 9;
        int k = i & 511;
        if (flags[0]) W1T[i] = f2bf(((const float*)W1)[k * DIM_HID + n]);
        else          W1T[i] = ((const u16*)W1)[k * DIM_HID + n];
    }
}

// ---- GEMM1 (MFMA 16x16x32 bf16), deep-preload A-operand for max MLP ----
// hs = bf16((x @ W1) * dinv[row]); wave = 16 rows x 64 cols, K=512.
__launch_bounds__(256)
__global__ void k_gemm1(const void* __restrict__ xraw, const u16* __restrict__ W1T,
                        const int* __restrict__ flags, const float* __restrict__ dinv,
                        u16* __restrict__ hs) {
    int f32f = flags[0];
    int wave = threadIdx.x >> 6;
    int lane = threadIdx.x & 63;
    int m16 = lane & 15;
    int quad = lane >> 4;
    int rbase = blockIdx.x * 64 + wave * 16;
    int ra = rbase + m16;
    if (ra > N_NODES - 1) ra = N_NODES - 1;
    const u16* wrow = W1T + (size_t)m16 * DIM_IN + quad * 8;

    f32x4 acc0 = {0.f, 0.f, 0.f, 0.f};
    f32x4 acc1 = {0.f, 0.f, 0.f, 0.f};
    f32x4 acc2 = {0.f, 0.f, 0.f, 0.f};
    f32x4 acc3 = {0.f, 0.f, 0.f, 0.f};

    // A fragments for all 16 K-steps, preloaded so all HBM loads are in flight
    bf16x8 af[16];
    if (f32f) {
        const float4* xq = (const float4*)((const float*)xraw + (size_t)ra * DIM_IN) + quad * 2;
        float4 xa[32];
#pragma unroll
        for (int ks = 0; ks < 16; ++ks) {
            xa[2 * ks]     = xq[ks * 8];
            xa[2 * ks + 1] = xq[ks * 8 + 1];
        }
#pragma unroll
        for (int ks = 0; ks < 16; ++ks) {
            float4 p0 = xa[2 * ks], p1 = xa[2 * ks + 1];
            union { bf16x8 v; u16 s[8]; } u;
            u.s[0] = f2bf(p0.x); u.s[1] = f2bf(p0.y); u.s[2] = f2bf(p0.z); u.s[3] = f2bf(p0.w);
            u.s[4] = f2bf(p1.x); u.s[5] = f2bf(p1.y); u.s[6] = f2bf(p1.z); u.s[7] = f2bf(p1.w);
            af[ks] = u.v;
        }
    } else {
        const bf16x8* xq = (const bf16x8*)((const u16*)xraw + (size_t)ra * DIM_IN + quad * 8);
        // stride between K-steps is 32 elems = 2 bf16x8
#pragma unroll
        for (int ks = 0; ks < 16; ++ks) af[ks] = xq[ks * 4];
    }

#pragma unroll
    for (int ks = 0; ks < 16; ++ks) {
        bf16x8 b0 = *reinterpret_cast<const bf16x8*>(wrow + ks * 32);
        bf16x8 b1 = *reinterpret_cast<const bf16x8*>(wrow + ks * 32 + 16 * DIM_IN);
        bf16x8 b2 = *reinterpret_cast<const bf16x8*>(wrow + ks * 32 + 32 * DIM_IN);
        bf16x8 b3 = *reinterpret_cast<const bf16x8*>(wrow + ks * 32 + 48 * DIM_IN);
        acc0 = __builtin_amdgcn_mfma_f32_16x16x32_bf16(af[ks], b0, acc0, 0, 0, 0);
        acc1 = __builtin_amdgcn_mfma_f32_16x16x32_bf16(af[ks], b1, acc1, 0, 0, 0);
        acc2 = __builtin_amdgcn_mfma_f32_16x16x32_bf16(af[ks], b2, acc2, 0, 0, 0);
        acc3 = __builtin_amdgcn_mfma_f32_16x16x32_bf16(af[ks], b3, acc3, 0, 0, 0);
    }

#pragma unroll
    for (int i = 0; i < 4; ++i) {
        int r = rbase + quad * 4 + i;
        if (r < N_NODES) {
            float dv = dinv[r];
            u16* orow = hs + (size_t)r * DIM_HID;
            orow[ 0 + m16] = f2bf(acc0[i] * dv);
            orow[16 + m16] = f2bf(acc1[i] * dv);
            orow[32 + m16] = f2bf(acc2[i] * dv);
            orow[48 + m16] = f2bf(acc3[i] * dv);
        }
    }
}

// ---- layer-1 pull aggregation + fused GEMM2, software-pipelined gather ----
__launch_bounds__(256)
__global__ void k_agg1(const u16* __restrict__ hs, const int* __restrict__ rowptr,
                       const int* __restrict__ col, const float* __restrict__ dinv,
                       const void* __restrict__ b1, const void* __restrict__ W2,
                       const int* __restrict__ flags, float* __restrict__ zs) {
    int f32f = flags[0];
    int wave = threadIdx.x >> 6;
    int lane = threadIdx.x & 63;
    int d = blockIdx.x * 4 + wave;
    if (d >= N_NODES) return;
    int start = rowptr[d], end = rowptr[d + 1];
    if (start < 0) start = 0;
    if (end > N_EDGES) end = N_EDGES;
    if (end < start) end = start;

    float acc = 0.f;
    int n8 = (end - start) >> 3;
    int cA[8];
    if (n8 > 0) {
        const int* cp = col + start;
#pragma unroll
        for (int j = 0; j < 8; ++j) cA[j] = cp[j];
        for (int it = 0; it < n8; ++it) {
            int cB[8];
            if (it + 1 < n8) {
                const int* cpn = col + start + (it + 1) * 8;
#pragma unroll
                for (int j = 0; j < 8; ++j) cB[j] = cpn[j];
            } else {
#pragma unroll
                for (int j = 0; j < 8; ++j) cB[j] = 0;
            }
            float v[8];
#pragma unroll
            for (int j = 0; j < 8; ++j) v[j] = bf2f(hs[(size_t)cA[j] * DIM_HID + lane]);
#pragma unroll
            for (int j = 0; j < 8; ++j) acc += v[j];
#pragma unroll
            for (int j = 0; j < 8; ++j) cA[j] = cB[j];
        }
    }
    for (int e = start + n8 * 8; e < end; ++e)
        acc += bf2f(hs[(size_t)col[e] * DIM_HID + lane]);
    acc += bf2f(hs[(size_t)d * DIM_HID + lane]);  // self loop

    float b1v = f32f ? ((const float*)b1)[lane] : bf2f(((const u16*)b1)[lane]);
    float dv = dinv[d];
    float h2 = fmaxf(acc * dv + b1v, 0.f);

    float p[7];
#pragma unroll
    for (int f = 0; f < 7; ++f) {
        float w = f32f ? ((const float*)W2)[lane * DIM_OUT + f]
                       : bf2f(((const u16*)W2)[lane * DIM_OUT + f]);
        p[f] = h2 * w;
    }
#pragma unroll
    for (int off = 32; off >= 1; off >>= 1) {
#pragma unroll
        for (int f = 0; f < 7; ++f) p[f] += __shfl_xor(p[f], off);
    }
    if (lane == 0) {
#pragma unroll
        for (int f = 0; f < 7; ++f) zs[(size_t)d * 8 + f] = p[f] * dv;
        zs[(size_t)d * 8 + 7] = 0.f;
    }
}

// ---- layer-2 pull aggregation: out (f32) ----
__launch_bounds__(256)
__global__ void k_agg2(const float* __restrict__ zs, const int* __restrict__ rowptr,
                       const int* __restrict__ col, const float* __restrict__ dinv,
                       const void* __restrict__ b2, const int* __restrict__ flags,
                       float* __restrict__ out) {
    int f32f = flags[0];
    int wave = threadIdx.x >> 6;
    int lane = threadIdx.x & 63;
    int d = blockIdx.x * 4 + wave;
    if (d >= N_NODES) return;
    int f = lane & 7;
    int g = lane >> 3;
    int start = rowptr[d], end = rowptr[d + 1];
    if (start < 0) start = 0;
    if (end > N_EDGES) end = N_EDGES;
    if (end < start) end = start;

    float acc = 0.f;
    for (int e = start + g; e < end; e += 8)
        acc += zs[(size_t)col[e] * 8 + f];

    acc += __shfl_xor(acc, 8);
    acc += __shfl_xor(acc, 16);
    acc += __shfl_xor(acc, 32);

    if (lane < 7) {
        float b2v = f32f ? ((const float*)b2)[lane] : bf2f(((const u16*)b2)[lane]);
        float tot = (acc + zs[(size_t)d * 8 + lane]) * dinv[d] + b2v;
        out[(size_t)d * DIM_OUT + lane] = tot;
    }
}

extern "C" void kernel_launch(void* const* d_in, const int* in_sizes, int n_in,
                              void* d_out, int out_size, void* d_ws, size_t ws_size,
                              hipStream_t stream) {
    const void* x  = d_in[0];
    const int*  ei = (const int*)d_in[1];
    const void* W1 = d_in[2];
    const void* b1 = d_in[3];
    const void* W2 = d_in[4];
    const void* b2 = d_in[5];

    char* ws = (char*)d_ws;
    size_t off = 0;
    auto alloc = [&](size_t bytes) -> void* {
        void* p = ws + off;
        off = (off + bytes + 255) & ~(size_t)255;
        return p;
    };
    int*   flags  = (int*)alloc(32);
    int*   rowptr = (int*)alloc((size_t)(N_NODES + 1) * 4);
    int*   gbsum  = (int*)alloc((size_t)NBUCK * 4);
    int*   bbase  = (int*)alloc((size_t)NBUCK * 4);
    int*   cnt    = (int*)alloc((size_t)NBUCK * PART_BLOCKS * 4);
    float* dinv   = (float*)alloc((size_t)N_NODES * 4);
    u16*   W1T    = (u16*)alloc((size_t)DIM_IN * DIM_HID * 2);
    unsigned int* ebuf = (unsigned int*)alloc((size_t)N_EDGES * 4);
    int*   colb   = (int*)alloc((size_t)N_EDGES * 4);
    u16*   hs     = (u16*)alloc((size_t)N_NODES * DIM_HID * 2);
    float* zs     = (float*)alloc((size_t)N_NODES * 8 * 4);
    float* out    = (float*)d_out;

    hipMemsetAsync(gbsum, 0, (size_t)NBUCK * 4, stream);
    k_detect<<<1, 64, 0, stream>>>((const u16*)x, ei, flags);
    k_count<<<PART_BLOCKS, 256, 0, stream>>>(ei, flags, gbsum, cnt);
    k_s2   <<<1, 256, 0, stream>>>(gbsum, bbase, rowptr);
    k_pb   <<<NBUCK, 256, 0, stream>>>(bbase, cnt);
    k_part <<<PART_BLOCKS, 256, 0, stream>>>(ei, flags, cnt, ebuf);
    k_cfill<<<NBUCK, 256, 0, stream>>>(ebuf, bbase, gbsum, rowptr, dinv, colb);
    k_tw1  <<<(DIM_IN * DIM_HID + 255) / 256, 256, 0, stream>>>(W1, flags, W1T);
    k_gemm1<<<(N_NODES + 63) / 64, 256, 0, stream>>>(x, W1T, flags, dinv, hs);
    k_agg1 <<<(N_NODES + 3) / 4, 256, 0, stream>>>(hs, rowptr, colb, dinv, b1, W2, flags, zs);
    k_agg2 <<<(N_NODES + 3) / 4, 256, 0, stream>>>(zs, rowptr, colb, dinv, b2, flags, out);
}